// Round 9
// baseline (51.059 us; speedup 1.0000x reference)
//
#include <hip/hip_runtime.h>
#include <stdint.h>

// BaseRenderer: NeRF-style compositing with per-ray depth sort.
// v9: sort chain is 100% VALU (zero DS ops): xor1/2 quad_perm, xor4 via
// row_shl4/row_shr4+select, xor8 row_ror:8, xor16/32 permlane swaps.
// 1 ray/wave, barrier-free, gll slab staging, single vmcnt(0) drain,
// gather epilogue at sorted indices. DS pipe only: sigma bpermute + slab reads.

typedef unsigned long long u64;
typedef int v2i __attribute__((ext_vector_type(2)));

// ---------------- DPP helpers ----------------
template<int CTRL, int RM>
__device__ __forceinline__ float updpp_f(float oldv, float src) {
    return __uint_as_float((uint32_t)__builtin_amdgcn_update_dpp(
        (int)__float_as_uint(oldv), (int)__float_as_uint(src), CTRL, RM, 0xF, false));
}

template<int CTRL>
__device__ __forceinline__ uint32_t dppmov_u(uint32_t v) {
    return (uint32_t)__builtin_amdgcn_mov_dpp((int)v, CTRL, 0xF, 0xF, true);
}

// 6-op DPP reduction; full-wave total lands in lane 63.
__device__ __forceinline__ float red6(float x) {
    x += updpp_f<0x111, 0xF>(0.0f, x);   // row_shr:1
    x += updpp_f<0x112, 0xF>(0.0f, x);   // row_shr:2
    x += updpp_f<0x114, 0xF>(0.0f, x);   // row_shr:4
    x += updpp_f<0x118, 0xF>(0.0f, x);   // row_shr:8
    x += updpp_f<0x142, 0xA>(0.0f, x);   // row_bcast:15 -> rows 1,3
    x += updpp_f<0x143, 0xC>(0.0f, x);   // row_bcast:31 -> rows 2,3
    return x;
}

// ---------------- cross-lane partner fetch, lane^LJ — ALL VALU ----------------
// xor1/2: quad_perm. xor4: select(row_shl:4, row_shr:4) by lane bit2.
// xor8: row_ror:8 (== xor8 within a 16-row). xor16/32: permlane{16,32}_swap
// with the direction-independent identity partner = r.x ^ r.y ^ x.
template<int LJ>
__device__ __forceinline__ uint32_t xp(uint32_t k, int lane) {
    if constexpr (LJ == 1)       return dppmov_u<0xB1>(k);    // quad_perm [1,0,3,2]
    else if constexpr (LJ == 2)  return dppmov_u<0x4E>(k);    // quad_perm [2,3,0,1]
    else if constexpr (LJ == 4) {
        uint32_t up = dppmov_u<0x104>(k);   // row_shl:4 -> dst l gets src l+4
        uint32_t dn = dppmov_u<0x114>(k);   // row_shr:4 -> dst l gets src l-4
        return (lane & 4) ? dn : up;
    }
    else if constexpr (LJ == 8)  return dppmov_u<0x128>(k);   // row_ror:8
    else if constexpr (LJ == 16) {
        v2i r = __builtin_amdgcn_permlane16_swap((int)k, (int)k, false, false);
        return ((uint32_t)r.x ^ (uint32_t)r.y) ^ k;
    } else {
        v2i r = __builtin_amdgcn_permlane32_swap((int)k, (int)k, false, false);
        return ((uint32_t)r.x ^ (uint32_t)r.y) ^ k;
    }
}

template<int LJ>
__device__ __forceinline__ void crossce(uint32_t& a, uint32_t& b, bool dirbit, int lane) {
    uint32_t pa = xp<LJ>(a, lane);
    uint32_t pb = xp<LJ>(b, lane);
    const bool keepmin = (((lane & LJ) == 0) == dirbit);
    a = ((pa < a) == keepmin) ? pa : a;    // keys unique -> no ties
    b = ((pb < b) == keepmin) ? pb : b;
    if constexpr (LJ > 1) crossce<LJ / 2>(a, b, dirbit, lane);
}

template<int K>
__device__ __forceinline__ void phase32(uint32_t& a, uint32_t& b, int lane) {
    const bool dirbit = ((lane & (K >> 1)) == 0);
    if constexpr (K >= 4) crossce<K / 4>(a, b, dirbit, lane);
    const bool sw = ((b < a) == dirbit);   // intra-lane step
    uint32_t t = a;
    a = sw ? b : a;
    b = sw ? t : b;
}

__device__ __forceinline__ void sort128(uint32_t& a, uint32_t& b, int lane) {
    phase32<2>(a, b, lane);
    phase32<4>(a, b, lane);
    phase32<8>(a, b, lane);
    phase32<16>(a, b, lane);
    phase32<32>(a, b, lane);
    phase32<64>(a, b, lane);
    phase32<128>(a, b, lane);
}

// ---------------- 64-bit fallback sort ----------------
__device__ __forceinline__ u64 shfl_xor_u64(u64 v, int mask) {
    int lo = __shfl_xor((int)(uint32_t)v, mask, 64);
    int hi = __shfl_xor((int)(uint32_t)(v >> 32), mask, 64);
    return ((u64)(uint32_t)hi << 32) | (uint32_t)lo;
}

__device__ __forceinline__ void sort128_u64(float2 zv, int lane,
                                            uint32_t& i0, uint32_t& i1,
                                            float& zs0, float& zs1) {
    u64 a = ((u64)__float_as_uint(zv.x) << 7) | (u64)(2 * lane);
    u64 b = ((u64)__float_as_uint(zv.y) << 7) | (u64)(2 * lane + 1);
    #pragma unroll
    for (int k = 2; k <= 128; k <<= 1) {
        #pragma unroll
        for (int j = k >> 1; j >= 2; j >>= 1) {
            const int lj = j >> 1;
            u64 pa = shfl_xor_u64(a, lj);
            u64 pb = shfl_xor_u64(b, lj);
            const bool keepmin = (((lane & lj) == 0) == ((lane & (k >> 1)) == 0));
            a = ((pa < a) == keepmin) ? pa : a;
            b = ((pb < b) == keepmin) ? pb : b;
        }
        const bool asc = ((lane & (k >> 1)) == 0);
        const bool sw = ((b < a) == asc);
        u64 t = a;
        a = sw ? b : a;
        b = sw ? t : b;
    }
    i0 = (uint32_t)(a & 127u);
    i1 = (uint32_t)(b & 127u);
    zs0 = __uint_as_float((uint32_t)(a >> 7));
    zs1 = __uint_as_float((uint32_t)(b >> 7));
}

#define GLL16(gsrc, ldst) __builtin_amdgcn_global_load_lds(                    \
    (const __attribute__((address_space(1))) void*)(gsrc),                     \
    (__attribute__((address_space(3))) void*)(ldst), 16, 0, 0)

__global__ __launch_bounds__(256) void render_kernel(
    const float* __restrict__ z_vals,
    const float* __restrict__ sigma_vals,
    const float* __restrict__ rgb_vals,
    const float* __restrict__ inst_vals,
    const float* __restrict__ bg_color,
    float* __restrict__ out,
    int N)
{
    constexpr float INF_DIST = 1e10f;
    constexpr float EPS = 1e-10f;

    const int lane = threadIdx.x & 63;
    const int wib  = threadIdx.x >> 6;            // 0..3 (4 waves/block)
    int ray = blockIdx.x * 4 + wib;
    if (ray >= N) ray = N - 1;                    // clamp (barrier-free, safe dup)

    // per-wave slab: [ rgb 0..383 | inst 384..767 ]  -> 12,288 B/block
    __shared__ float lds[4][768];
    float* slab = &lds[wib][0];

    const size_t rbase = (size_t)ray * 128;

    // ---- issue ALL VMEM up front ----
    float2 zv = ((const float2*)(z_vals     + rbase))[lane];
    float2 sv = ((const float2*)(sigma_vals + rbase))[lane];
    {
        const char* rp = (const char*)(rgb_vals  + rbase * 3);
        const char* ip = (const char*)(inst_vals + rbase * 3);
        char* rd = (char*)slab;
        char* id = (char*)(slab + 384);
        GLL16(rp + (size_t)lane * 16, rd);                  // rgb  [0,1024)
        GLL16(ip + (size_t)lane * 16, id);                  // inst [0,1024)
        if (lane < 32) {
            GLL16(rp + 1024 + (size_t)lane * 16, rd + 1024);
            GLL16(ip + 1024 + (size_t)lane * 16, id + 1024);
        }
    }
    __builtin_amdgcn_sched_barrier(0);            // pin issues above compute

    // ---- bg: wave-uniform scalar loads (SMEM pipe) ----
    float bg0 = bg_color[(size_t)ray * 3 + 0];
    float bg1 = bg_color[(size_t)ray * 3 + 1];
    float bg2 = bg_color[(size_t)ray * 3 + 2];

    // ---- dyadic check: z == m / 2^21, m < 2^23 (exact for JAX uniform*4) ----
    float k0f = zv.x * 2097152.0f;
    float k1f = zv.y * 2097152.0f;
    uint32_t m0i = (uint32_t)k0f;
    uint32_t m1i = (uint32_t)k1f;
    bool exact = (k0f == (float)m0i) && (k1f == (float)m1i) &&
                 (m0i < (1u << 23)) && (m1i < (1u << 23));

    uint32_t i0, i1;
    float zs0, zs1;

    if (__ballot(exact) == ~0ull) {
        uint32_t a = (m0i << 7) | (uint32_t)(2 * lane);
        uint32_t b = (m1i << 7) | (uint32_t)(2 * lane + 1);
        sort128(a, b, lane);
        i0 = a & 127u;
        i1 = b & 127u;
        zs0 = (float)(a >> 7) * 0x1p-21f;         // bit-exact z recovery
        zs1 = (float)(b >> 7) * 0x1p-21f;
    } else {
        sort128_u64(zv, lane, i0, i1, zs0, zs1);
    }

    // ---- gather sigma by original index (bpermute; issue asap) ----
    float s0a = __shfl(sv.x, (int)(i0 >> 1), 64);
    float s0b = __shfl(sv.y, (int)(i0 >> 1), 64);
    float s1a = __shfl(sv.x, (int)(i1 >> 1), 64);
    float s1b = __shfl(sv.y, (int)(i1 >> 1), 64);
    float sg0 = (i0 & 1) ? s0b : s0a;
    float sg1 = (i1 & 1) ? s1b : s1a;

    // ---- drain: gll slab now resident (issued ~sort ago; per-wave, no barrier) ----
    asm volatile("s_waitcnt vmcnt(0)" ::: "memory");
    __builtin_amdgcn_sched_barrier(0);

    // ---- rgb/inst gathers at sorted indices (DS; overlap the scan below) ----
    const float* pA = slab + i0 * 3;
    const float* pB = slab + i1 * 3;
    float rA0 = pA[0],   rA1 = pA[1],   rA2 = pA[2];
    float qA0 = pA[384], qA1 = pA[385], qA2 = pA[386];
    float rB0 = pB[0],   rB1 = pB[1],   rB2 = pB[2];
    float qB0 = pB[384], qB1 = pB[385], qB2 = pB[386];

    // ---- dists; lane63 boundary via DPP old=INF ----
    float znx = updpp_f<0x130, 0xF>(INF_DIST, zs0);   // wave_shl:1
    float d0 = zs1 - zs0;
    float d1 = znx - zs1;

    // ---- alpha / transmittance factors ----
    float e0 = __expf(-fmaxf(sg0, 0.0f) * d0);
    float e1 = __expf(-fmaxf(sg1, 0.0f) * d1);
    float a0 = 1.0f - e0;
    float a1 = 1.0f - e1;
    float m0 = 1.0f - a0 + EPS;
    float m1 = 1.0f - a1 + EPS;

    // ---- DPP multiply-scan (inclusive), identity 1.0 ----
    float s = m0 * m1;
    s *= updpp_f<0x111, 0xF>(1.0f, s);
    s *= updpp_f<0x112, 0xF>(1.0f, s);
    s *= updpp_f<0x114, 0xF>(1.0f, s);
    s *= updpp_f<0x118, 0xF>(1.0f, s);
    s *= updpp_f<0x142, 0xA>(1.0f, s);
    s *= updpp_f<0x143, 0xC>(1.0f, s);

    float excl = updpp_f<0x138, 0xF>(1.0f, s);        // wave_shr:1, lane0 -> 1.0

    float w0 = a0 * excl;
    float w1 = a1 * (excl * m0);

    // ---- w output (sorted order), nontemporal, issued early ----
    {
        u64 wbits = ((u64)__float_as_uint(w1) << 32) | (u64)__float_as_uint(w0);
        __builtin_nontemporal_store(wbits, (u64*)(out + (size_t)7 * N + rbase) + lane);
    }

    // ---- weighted partials (sorted domain; same sums as reference) ----
    float dep = w0 * zs0 + w1 * zs1;
    float cr = w0 * rA0 + w1 * rB0;
    float cg = w0 * rA1 + w1 * rB1;
    float cb = w0 * rA2 + w1 * rB2;
    float k0 = w0 * qA0 + w1 * qB0;
    float k1 = w0 * qA1 + w1 * qB1;
    float k2 = w0 * qA2 + w1 * qB2;

    // ---- DPP reductions; totals land in lane 63 ----
    dep = red6(dep);
    cr  = red6(cr);
    cg  = red6(cg);
    cb  = red6(cb);
    k0  = red6(k0);
    k1  = red6(k1);
    k2  = red6(k2);

    if (lane == 63) {
        float no_hit = s;
        out[(size_t)ray * 3 + 0] = cr + no_hit * bg0;
        out[(size_t)ray * 3 + 1] = cg + no_hit * bg1;
        out[(size_t)ray * 3 + 2] = cb + no_hit * bg2;
        out[(size_t)3 * N + ray] = dep;
        out[(size_t)4 * N + (size_t)ray * 3 + 0] = k0;
        out[(size_t)4 * N + (size_t)ray * 3 + 1] = k1;
        out[(size_t)4 * N + (size_t)ray * 3 + 2] = k2;
    }
}

extern "C" void kernel_launch(void* const* d_in, const int* in_sizes, int n_in,
                              void* d_out, int out_size, void* d_ws, size_t ws_size,
                              hipStream_t stream)
{
    const float* z    = (const float*)d_in[0];
    const float* sg   = (const float*)d_in[1];
    const float* rgb  = (const float*)d_in[2];
    const float* inst = (const float*)d_in[3];
    const float* bg   = (const float*)d_in[4];
    float* out = (float*)d_out;

    const int S = 128;
    int N = in_sizes[0] / S;                  // 65536
    int blocks = (N + 3) / 4;                 // 1 ray/wave, 4 waves/block
    render_kernel<<<blocks, 256, 0, stream>>>(z, sg, rgb, inst, bg, out, N);
}

// Round 10
// 50.850 us; speedup vs baseline: 1.0041x; 1.0041x over previous
//
#include <hip/hip_runtime.h>
#include <stdint.h>

// BaseRenderer: NeRF-style compositing with per-ray depth sort.
// v10: 16-wave (1024-thread) blocks to amortize workgroup launch (grid 16K->4K,
// 2 blocks/CU = full 32-wave occupancy). Zero barriers (wave-private slabs).
// R8-best sort mix (xor4 via ds_swizzle, xor16/32 via permlane swaps).
// sigma staged via gll alongside rgb/inst; all gathers from LDS at sorted idx.

typedef unsigned long long u64;
typedef int v2i __attribute__((ext_vector_type(2)));

// ---------------- DPP helpers ----------------
template<int CTRL, int RM>
__device__ __forceinline__ float updpp_f(float oldv, float src) {
    return __uint_as_float((uint32_t)__builtin_amdgcn_update_dpp(
        (int)__float_as_uint(oldv), (int)__float_as_uint(src), CTRL, RM, 0xF, false));
}

template<int CTRL>
__device__ __forceinline__ uint32_t dppmov_u(uint32_t v) {
    return (uint32_t)__builtin_amdgcn_mov_dpp((int)v, CTRL, 0xF, 0xF, true);
}

// 6-op DPP reduction; full-wave total lands in lane 63.
__device__ __forceinline__ float red6(float x) {
    x += updpp_f<0x111, 0xF>(0.0f, x);   // row_shr:1
    x += updpp_f<0x112, 0xF>(0.0f, x);   // row_shr:2
    x += updpp_f<0x114, 0xF>(0.0f, x);   // row_shr:4
    x += updpp_f<0x118, 0xF>(0.0f, x);   // row_shr:8
    x += updpp_f<0x142, 0xA>(0.0f, x);   // row_bcast:15 -> rows 1,3
    x += updpp_f<0x143, 0xC>(0.0f, x);   // row_bcast:31 -> rows 2,3
    return x;
}

// ---------------- cross-lane partner fetch, lane^LJ (R8 mix) ----------------
template<int LJ>
__device__ __forceinline__ uint32_t xp(uint32_t k) {
    if constexpr (LJ == 1)       return dppmov_u<0xB1>(k);    // quad_perm [1,0,3,2]
    else if constexpr (LJ == 2)  return dppmov_u<0x4E>(k);    // quad_perm [2,3,0,1]
    else if constexpr (LJ == 4)  return (uint32_t)__builtin_amdgcn_ds_swizzle((int)k, 0x101F);
    else if constexpr (LJ == 8)  return dppmov_u<0x128>(k);   // row_ror:8 == xor8
    else if constexpr (LJ == 16) {
        v2i r = __builtin_amdgcn_permlane16_swap((int)k, (int)k, false, false);
        return ((uint32_t)r.x ^ (uint32_t)r.y) ^ k;
    } else {
        v2i r = __builtin_amdgcn_permlane32_swap((int)k, (int)k, false, false);
        return ((uint32_t)r.x ^ (uint32_t)r.y) ^ k;
    }
}

template<int LJ>
__device__ __forceinline__ void crossce(uint32_t& a, uint32_t& b, bool dirbit, int lane) {
    uint32_t pa = xp<LJ>(a);
    uint32_t pb = xp<LJ>(b);
    const bool keepmin = (((lane & LJ) == 0) == dirbit);
    a = ((pa < a) == keepmin) ? pa : a;    // keys unique -> no ties
    b = ((pb < b) == keepmin) ? pb : b;
    if constexpr (LJ > 1) crossce<LJ / 2>(a, b, dirbit, lane);
}

template<int K>
__device__ __forceinline__ void phase32(uint32_t& a, uint32_t& b, int lane) {
    const bool dirbit = ((lane & (K >> 1)) == 0);
    if constexpr (K >= 4) crossce<K / 4>(a, b, dirbit, lane);
    const bool sw = ((b < a) == dirbit);   // intra-lane step
    uint32_t t = a;
    a = sw ? b : a;
    b = sw ? t : b;
}

__device__ __forceinline__ void sort128(uint32_t& a, uint32_t& b, int lane) {
    phase32<2>(a, b, lane);
    phase32<4>(a, b, lane);
    phase32<8>(a, b, lane);
    phase32<16>(a, b, lane);
    phase32<32>(a, b, lane);
    phase32<64>(a, b, lane);
    phase32<128>(a, b, lane);
}

// ---------------- 64-bit fallback sort ----------------
__device__ __forceinline__ u64 shfl_xor_u64(u64 v, int mask) {
    int lo = __shfl_xor((int)(uint32_t)v, mask, 64);
    int hi = __shfl_xor((int)(uint32_t)(v >> 32), mask, 64);
    return ((u64)(uint32_t)hi << 32) | (uint32_t)lo;
}

__device__ __forceinline__ void sort128_u64(float2 zv, int lane,
                                            uint32_t& i0, uint32_t& i1,
                                            float& zs0, float& zs1) {
    u64 a = ((u64)__float_as_uint(zv.x) << 7) | (u64)(2 * lane);
    u64 b = ((u64)__float_as_uint(zv.y) << 7) | (u64)(2 * lane + 1);
    #pragma unroll
    for (int k = 2; k <= 128; k <<= 1) {
        #pragma unroll
        for (int j = k >> 1; j >= 2; j >>= 1) {
            const int lj = j >> 1;
            u64 pa = shfl_xor_u64(a, lj);
            u64 pb = shfl_xor_u64(b, lj);
            const bool keepmin = (((lane & lj) == 0) == ((lane & (k >> 1)) == 0));
            a = ((pa < a) == keepmin) ? pa : a;
            b = ((pb < b) == keepmin) ? pb : b;
        }
        const bool asc = ((lane & (k >> 1)) == 0);
        const bool sw = ((b < a) == asc);
        u64 t = a;
        a = sw ? b : a;
        b = sw ? t : b;
    }
    i0 = (uint32_t)(a & 127u);
    i1 = (uint32_t)(b & 127u);
    zs0 = __uint_as_float((uint32_t)(a >> 7));
    zs1 = __uint_as_float((uint32_t)(b >> 7));
}

#define GLL16(gsrc, ldst) __builtin_amdgcn_global_load_lds(                    \
    (const __attribute__((address_space(1))) void*)(gsrc),                     \
    (__attribute__((address_space(3))) void*)(ldst), 16, 0, 0)

// Per-wave slab layout (floats): [ rgb 0..383 | inst 384..767 | sigma 768..895 | pad ]
#define SLABF 904

__global__ __launch_bounds__(1024) void render_kernel(
    const float* __restrict__ z_vals,
    const float* __restrict__ sigma_vals,
    const float* __restrict__ rgb_vals,
    const float* __restrict__ inst_vals,
    const float* __restrict__ bg_color,
    float* __restrict__ out,
    int N)
{
    constexpr float INF_DIST = 1e10f;
    constexpr float EPS = 1e-10f;

    const int lane = threadIdx.x & 63;
    const int wib  = threadIdx.x >> 6;            // 0..15 (16 waves/block)
    int ray = blockIdx.x * 16 + wib;
    if (ray >= N) ray = N - 1;                    // clamp (barrier-free, safe dup)

    __shared__ float lds[16][SLABF];              // 57,856 B/block
    float* slab = &lds[wib][0];

    const size_t rbase = (size_t)ray * 128;

    // ---- issue ALL VMEM up front ----
    float2 zv = ((const float2*)(z_vals + rbase))[lane];
    {
        const char* rp = (const char*)(rgb_vals   + rbase * 3);
        const char* ip = (const char*)(inst_vals  + rbase * 3);
        const char* sp = (const char*)(sigma_vals + rbase);
        char* rd = (char*)slab;
        char* id = (char*)(slab + 384);
        char* sd = (char*)(slab + 768);
        GLL16(rp + (size_t)lane * 16, rd);                  // rgb  [0,1024)
        GLL16(ip + (size_t)lane * 16, id);                  // inst [0,1024)
        if (lane < 32) {
            GLL16(rp + 1024 + (size_t)lane * 16, rd + 1024);   // rgb  [1024,1536)
            GLL16(ip + 1024 + (size_t)lane * 16, id + 1024);   // inst [1024,1536)
            GLL16(sp + (size_t)lane * 16, sd);                 // sigma [0,512)
        }
    }
    __builtin_amdgcn_sched_barrier(0);            // pin issues above compute

    // ---- bg: wave-uniform scalar loads (SMEM pipe) ----
    float bg0 = bg_color[(size_t)ray * 3 + 0];
    float bg1 = bg_color[(size_t)ray * 3 + 1];
    float bg2 = bg_color[(size_t)ray * 3 + 2];

    // ---- dyadic check: z == m / 2^21, m < 2^23 (exact for JAX uniform*4) ----
    float k0f = zv.x * 2097152.0f;
    float k1f = zv.y * 2097152.0f;
    uint32_t m0i = (uint32_t)k0f;
    uint32_t m1i = (uint32_t)k1f;
    bool exact = (k0f == (float)m0i) && (k1f == (float)m1i) &&
                 (m0i < (1u << 23)) && (m1i < (1u << 23));

    uint32_t i0, i1;
    float zs0, zs1;

    if (__ballot(exact) == ~0ull) {
        uint32_t a = (m0i << 7) | (uint32_t)(2 * lane);
        uint32_t b = (m1i << 7) | (uint32_t)(2 * lane + 1);
        sort128(a, b, lane);
        i0 = a & 127u;
        i1 = b & 127u;
        zs0 = (float)(a >> 7) * 0x1p-21f;         // bit-exact z recovery
        zs1 = (float)(b >> 7) * 0x1p-21f;
    } else {
        sort128_u64(zv, lane, i0, i1, zs0, zs1);
    }

    // ---- drain: all slabs resident (issued ~sort ago; per-wave, no barrier) ----
    asm volatile("s_waitcnt vmcnt(0)" ::: "memory");
    __builtin_amdgcn_sched_barrier(0);

    // ---- gathers at sorted indices from the slab (DS pipe) ----
    float sg0 = slab[768 + i0];
    float sg1 = slab[768 + i1];
    const float* pA = slab + i0 * 3;
    const float* pB = slab + i1 * 3;
    float rA0 = pA[0],   rA1 = pA[1],   rA2 = pA[2];
    float qA0 = pA[384], qA1 = pA[385], qA2 = pA[386];
    float rB0 = pB[0],   rB1 = pB[1],   rB2 = pB[2];
    float qB0 = pB[384], qB1 = pB[385], qB2 = pB[386];

    // ---- dists; lane63 boundary via DPP old=INF ----
    float znx = updpp_f<0x130, 0xF>(INF_DIST, zs0);   // wave_shl:1
    float d0 = zs1 - zs0;
    float d1 = znx - zs1;

    // ---- alpha / transmittance factors ----
    float e0 = __expf(-fmaxf(sg0, 0.0f) * d0);
    float e1 = __expf(-fmaxf(sg1, 0.0f) * d1);
    float a0 = 1.0f - e0;
    float a1 = 1.0f - e1;
    float m0 = 1.0f - a0 + EPS;
    float m1 = 1.0f - a1 + EPS;

    // ---- DPP multiply-scan (inclusive), identity 1.0 ----
    float s = m0 * m1;
    s *= updpp_f<0x111, 0xF>(1.0f, s);
    s *= updpp_f<0x112, 0xF>(1.0f, s);
    s *= updpp_f<0x114, 0xF>(1.0f, s);
    s *= updpp_f<0x118, 0xF>(1.0f, s);
    s *= updpp_f<0x142, 0xA>(1.0f, s);
    s *= updpp_f<0x143, 0xC>(1.0f, s);

    float excl = updpp_f<0x138, 0xF>(1.0f, s);        // wave_shr:1, lane0 -> 1.0

    float w0 = a0 * excl;
    float w1 = a1 * (excl * m0);

    // ---- w output (sorted order), nontemporal, issued early ----
    {
        u64 wbits = ((u64)__float_as_uint(w1) << 32) | (u64)__float_as_uint(w0);
        __builtin_nontemporal_store(wbits, (u64*)(out + (size_t)7 * N + rbase) + lane);
    }

    // ---- weighted partials (sorted domain; same sums as reference) ----
    float dep = w0 * zs0 + w1 * zs1;
    float cr = w0 * rA0 + w1 * rB0;
    float cg = w0 * rA1 + w1 * rB1;
    float cb = w0 * rA2 + w1 * rB2;
    float k0 = w0 * qA0 + w1 * qB0;
    float k1 = w0 * qA1 + w1 * qB1;
    float k2 = w0 * qA2 + w1 * qB2;

    // ---- DPP reductions; totals land in lane 63 ----
    dep = red6(dep);
    cr  = red6(cr);
    cg  = red6(cg);
    cb  = red6(cb);
    k0  = red6(k0);
    k1  = red6(k1);
    k2  = red6(k2);

    if (lane == 63) {
        float no_hit = s;
        out[(size_t)ray * 3 + 0] = cr + no_hit * bg0;
        out[(size_t)ray * 3 + 1] = cg + no_hit * bg1;
        out[(size_t)ray * 3 + 2] = cb + no_hit * bg2;
        out[(size_t)3 * N + ray] = dep;
        out[(size_t)4 * N + (size_t)ray * 3 + 0] = k0;
        out[(size_t)4 * N + (size_t)ray * 3 + 1] = k1;
        out[(size_t)4 * N + (size_t)ray * 3 + 2] = k2;
    }
}

extern "C" void kernel_launch(void* const* d_in, const int* in_sizes, int n_in,
                              void* d_out, int out_size, void* d_ws, size_t ws_size,
                              hipStream_t stream)
{
    const float* z    = (const float*)d_in[0];
    const float* sg   = (const float*)d_in[1];
    const float* rgb  = (const float*)d_in[2];
    const float* inst = (const float*)d_in[3];
    const float* bg   = (const float*)d_in[4];
    float* out = (float*)d_out;

    const int S = 128;
    int N = in_sizes[0] / S;                  // 65536
    int blocks = (N + 15) / 16;               // 1 ray/wave, 16 waves/block
    render_kernel<<<blocks, 1024, 0, stream>>>(z, sg, rgb, inst, bg, out, N);
}